// Round 5
// baseline (526.307 us; speedup 1.0000x reference)
//
#include <hip/hip_runtime.h>

// Problem constants: B=2, C=256, planes=64, T=8, D=H=W=16
// spatial per batch S = T*D*H*W = 32768
#define S_TOT 32768

typedef unsigned short ushortT;
typedef __attribute__((ext_vector_type(8))) short short8;
typedef __attribute__((ext_vector_type(4))) float floatx4;

__device__ __forceinline__ ushortT f2bf(float f) {
    unsigned u = __float_as_uint(f);
    u = (u + 0x7fffu + ((u >> 16) & 1u)) >> 16;
    return (ushortT)u;
}
__device__ __forceinline__ float bf2f(ushortT h) {
    return __uint_as_float(((unsigned)h) << 16);
}
// normalize+relu a dword holding two bf16 of one channel, repack to bf16x2
__device__ __forceinline__ uint32_t nrm2(uint32_t u, float a, float bs) {
    float lo = fmaxf(fmaf(a, bf2f((ushortT)(u & 0xffffu)), bs), 0.f);
    float hi = fmaxf(fmaf(a, bf2f((ushortT)(u >> 16)), bs), 0.f);
    return (uint32_t)f2bf(lo) | ((uint32_t)f2bf(hi) << 16);
}

// Striped stats buffer: 8 stripes x 768 floats.
// Within a stripe: sum1[64] @0, sq1[64] @64, sum2[64] @128, sq2[64] @192,
//                  sum3[256] @256, sq3[256] @512.
#define NSTRIPE 8
#define STRIDE_ST 768

// ---------------------------------------------------------------------------
// Prep weights + zero stats stripes.
__global__ __launch_bounds__(256) void k_prep_w(const float* __restrict__ w1,
                                                const float* __restrict__ w2,
                                                const float* __restrict__ w3,
                                                ushortT* __restrict__ wb1,
                                                ushortT* __restrict__ wb2,
                                                ushortT* __restrict__ wb3,
                                                float* __restrict__ stats) {
    int idx = blockIdx.x * 256 + threadIdx.x;
    if (idx < 16384) {
        int e = idx;
        int j = e & 7, o = (e >> 3) & 63, q = (e >> 9) & 3, cc = e >> 11;
        int c = cc * 32 + q * 8 + j;
        wb1[e] = f2bf(w1[o * 256 + c]);
    } else if (idx < 16384 + 331776) {
        int e = idx - 16384;
        int j = e & 7, o = (e >> 3) & 63, cb = (e >> 9) & 7, tap = e >> 12;
        int c = cb * 8 + j;
        wb2[e] = f2bf(w2[((size_t)o * 64 + c) * 81 + tap]);
    } else if (idx < 16384 + 331776 + 16384) {
        int e = idx - 348160;
        int j = e & 7, o = (e >> 3) & 255, g = e >> 11;
        int ks = g >> 2, q = g & 3;
        int c = ks * 32 + q * 8 + j;
        wb3[e] = f2bf(w3[o * 64 + c]);
    } else if (idx < 364544 + NSTRIPE * STRIDE_ST) {
        stats[idx - 364544] = 0.f;
    }
}

// ---------------------------------------------------------------------------
// Collapse stripes -> per-channel (a, bs) coefficients. 1 block, nch threads.
__global__ __launch_bounds__(256) void k_coef(const float* __restrict__ stats,
                                              int off, int nch,
                                              const float* __restrict__ g,
                                              const float* __restrict__ bb,
                                              float* __restrict__ coef) {
    int c = threadIdx.x;
    if (c >= nch) return;
    float s = 0.f, qv = 0.f;
#pragma unroll
    for (int p = 0; p < NSTRIPE; ++p) {
        s  += stats[p * STRIDE_ST + off + c];
        qv += stats[p * STRIDE_ST + off + nch + c];
    }
    const float inv_n = 1.f / 65536.f;
    float mu = s * inv_n, var = qv * inv_n - mu * mu;
    float a  = g[c] * rsqrtf(var + 1e-5f);
    coef[2 * c]     = a;
    coef[2 * c + 1] = bb[c] - mu * a;
}

// ---------------------------------------------------------------------------
// bn1-apply pass: y1n = bf16(relu(a*y1bf + bs)). Separate pass so conv2's
// staging critical path has NO dependent VALU transform (fused variant cost
// conv2 +29us; this pass costs ~5us of pure BW).
__global__ __launch_bounds__(256) void k_prep(const ushortT* __restrict__ yin,
                                              const float* __restrict__ coef,
                                              ushortT* __restrict__ yout) {
    size_t i = ((size_t)blockIdx.x * 256 + threadIdx.x) * 8;
    int c = (int)((i >> 15) & 63);
    float2 cf = *(const float2*)(coef + 2 * c);
    uint4 v = *(const uint4*)(yin + i);
    uint4 r;
    r.x = nrm2(v.x, cf.x, cf.y);
    r.y = nrm2(v.y, cf.x, cf.y);
    r.z = nrm2(v.z, cf.x, cf.y);
    r.w = nrm2(v.w, cf.x, cf.y);
    *(uint4*)(yout + i) = r;
}

// ---------------------------------------------------------------------------
// K1: conv1x1 256->64 via MFMA. x fp32 converted to bf16 in staging.
// Fused: per-channel sum/sq of the fp32 accumulators -> striped atomics.
__global__ __launch_bounds__(256) void k_conv1_mfma(const float* __restrict__ x,
                                                    const ushortT* __restrict__ wb1,
                                                    ushortT* __restrict__ y1bf,
                                                    float* __restrict__ stats) {
    __shared__ __align__(16) ushortT xb[128 * 40];   // [n][c32] stride 40

    int tid = threadIdx.x;
    int blk = blockIdx.x;
    int b  = blk >> 8;
    int n0 = (blk & 255) * 128;

    int lane = tid & 63;
    int wv   = tid >> 6;
    int m    = lane & 15;
    int q    = lane >> 4;

    int c_loc = tid & 31;     // staging channel within chunk
    int ng    = tid >> 5;     // staging n-group (8 groups of 16)

    floatx4 acc[8];
#pragma unroll
    for (int i = 0; i < 8; ++i) acc[i] = (floatx4){0.f, 0.f, 0.f, 0.f};

    for (int cc = 0; cc < 8; ++cc) {
        // A fragment from global (L2-hot): o = wv*16+m, k = q*8+j
        short8 afr = *(const short8*)(wb1 + (((cc * 4 + q) * 64) + wv * 16 + m) * 8);

        __syncthreads();
        // stage B: x[c][n] fp32 -> xb[n][c] bf16
        {
            int c = cc * 32 + c_loc;
            const float* xp = x + ((size_t)(b * 256 + c)) * S_TOT + n0 + ng * 16;
#pragma unroll
            for (int k = 0; k < 4; ++k) {
                float4 v = *(const float4*)(xp + k * 4);
                int nb = ng * 16 + k * 4;
                xb[(nb + 0) * 40 + c_loc] = f2bf(v.x);
                xb[(nb + 1) * 40 + c_loc] = f2bf(v.y);
                xb[(nb + 2) * 40 + c_loc] = f2bf(v.z);
                xb[(nb + 3) * 40 + c_loc] = f2bf(v.w);
            }
        }
        __syncthreads();

#pragma unroll
        for (int pt = 0; pt < 8; ++pt) {
            short8 bfr = *(const short8*)(xb + (pt * 16 + m) * 40 + q * 8);
            acc[pt] = __builtin_amdgcn_mfma_f32_16x16x32_bf16(afr, bfr, acc[pt], 0, 0, 0);
        }
    }

    // store bf16 (unnormalized)
#pragma unroll
    for (int pt = 0; pt < 8; ++pt) {
#pragma unroll
        for (int r = 0; r < 4; ++r) {
            int o = wv * 16 + q * 4 + r;
            y1bf[((size_t)(b * 64 + o)) * S_TOT + n0 + pt * 16 + m] = f2bf(acc[pt][r]);
        }
    }

    // fused stats1: channel o = wv*16+q*4+r, positions vary over (pt, m)
    float ssum[4] = {0.f, 0.f, 0.f, 0.f}, ssq[4] = {0.f, 0.f, 0.f, 0.f};
#pragma unroll
    for (int pt = 0; pt < 8; ++pt)
#pragma unroll
        for (int r = 0; r < 4; ++r) {
            float v = acc[pt][r];
            ssum[r] += v;
            ssq[r]  += v * v;
        }
#pragma unroll
    for (int off = 1; off < 16; off <<= 1)
#pragma unroll
        for (int r = 0; r < 4; ++r) {
            ssum[r] += __shfl_xor(ssum[r], off);
            ssq[r]  += __shfl_xor(ssq[r], off);
        }
    if (m == 0) {
        float* st = stats + (blk & (NSTRIPE - 1)) * STRIDE_ST;
#pragma unroll
        for (int r = 0; r < 4; ++r) {
            int o = wv * 16 + q * 4 + r;
            atomicAdd(st + o, ssum[r]);
            atomicAdd(st + 64 + o, ssq[r]);
        }
    }
}

// ---------------------------------------------------------------------------
// K3: conv 3x3x3x3, 64->64 as bf16 MFMA implicit GEMM.
// Reads PRE-NORMALIZED y1n (clean staging path, no VALU transform between
// barriers). Grid 1024 (4-row h quarters) -> 4 blocks/CU (VGPR<=128 forced)
// for 2x latency hiding vs the old 512-grid. Wave (wp,wo): h-pair x o-half.
// Per plane per wave: 36 ds_read_b128 feed 72 MFMAs. Fused stats2.
__global__ __launch_bounds__(256, 4) void k_conv2_mfma(
        const ushortT* __restrict__ y1n,   // [b][c][t][d][h][w] bf16, normalized
        const ushortT* __restrict__ wb2,   // [tap][cb][o][j] bf16
        float* __restrict__ stats,         // add stats2
        ushortT* __restrict__ y2bf) {
    __shared__ __align__(16) ushortT xs[108 * 64];   // 6 rows x 18 ppos x 64c
    __shared__ float st2[128];

    int tid = threadIdx.x;
    int blk = blockIdx.x;
    int b  = blk >> 9;
    int t  = (blk >> 6) & 7;
    int d  = (blk >> 2) & 15;
    int h0 = (blk & 3) * 4;

    int lane = tid & 63;
    int wv   = tid >> 6;
    int m    = lane & 15;
    int q    = lane >> 4;
    int wp   = wv & 1;     // h-pair: rows wp*2 .. wp*2+1 within the 4
    int wo   = wv >> 1;    // o half: o in [wo*32, wo*32+32)

    int c2      = tid & 31;
    int prbase  = tid >> 5;   // 0..7; rows 0..5 staged

    if (tid < 128) st2[tid] = 0.f;

    floatx4 acc[2][2];     // [ot][nt]
#pragma unroll
    for (int i = 0; i < 2; ++i)
#pragma unroll
        for (int j = 0; j < 2; ++j) acc[i][j] = (floatx4){0.f, 0.f, 0.f, 0.f};

    const size_t cstride = 32768;
    uint32_t* xsd = (uint32_t*)xs;

    for (int ktd = 0; ktd < 9; ++ktd) {
        int kt = ktd / 3, kd = ktd - kt * 3;
        int tt = t + kt - 1;
        int dd = d + kd - 1;
        bool pv = (tt >= 0 && tt < 8 && dd >= 0 && dd < 16);
        if (!pv) continue;   // zero contribution: skip staging AND MFMAs

        // Preload this wave's A fragments for all 9 (kh,kw) taps of this ktd.
        short8 afr[9][2][2];   // [khw][ks][ot]
#pragma unroll
        for (int khw = 0; khw < 9; ++khw) {
            int tap = ktd * 9 + khw;
#pragma unroll
            for (int ks = 0; ks < 2; ++ks)
#pragma unroll
                for (int ot = 0; ot < 2; ++ot) {
                    afr[khw][ks][ot] = *(const short8*)(wb2 +
                        (((size_t)(tap * 8 + ks * 4 + q)) * 64 + wo * 32 + ot * 16 + m) * 8);
                }
        }

        __syncthreads();

        if (prbase < 6) {
            int hin = h0 + prbase - 1;
            uint32_t pack[18];
            if (hin >= 0 && hin < 16) {
                const ushortT* p0 = y1n +
                    (((size_t)(b * 64 + 2 * c2) * 8 + tt) * 16 + dd) * 256 + hin * 16;
                const ushortT* p1 = p0 + cstride;
                uint4 r0 = *(const uint4*)p0;
                uint4 r1 = *(const uint4*)(p0 + 8);
                uint4 s0v = *(const uint4*)p1;
                uint4 s1v = *(const uint4*)(p1 + 8);
                uint32_t ra[8] = {r0.x, r0.y, r0.z, r0.w, r1.x, r1.y, r1.z, r1.w};
                uint32_t sa[8] = {s0v.x, s0v.y, s0v.z, s0v.w, s1v.x, s1v.y, s1v.z, s1v.w};
                pack[0] = 0; pack[17] = 0;
#pragma unroll
                for (int k = 0; k < 8; ++k) {
                    pack[1 + 2 * k] = (ra[k] & 0xffffu) | (sa[k] << 16);
                    pack[2 + 2 * k] = (ra[k] >> 16) | (sa[k] & 0xffff0000u);
                }
            } else {
#pragma unroll
                for (int k = 0; k < 18; ++k) pack[k] = 0;
            }
            int pb = prbase * 18;
#pragma unroll
            for (int k = 0; k < 18; ++k) {
                int ppos = pb + k;
                // dword index within 32-dword row, 16B-chunk swizzled
                xsd[ppos * 32 + ((((c2 >> 2) ^ (ppos & 7)) << 2) | (c2 & 3))] = pack[k];
            }
        }
        __syncthreads();

#pragma unroll
        for (int kh = 0; kh < 3; ++kh) {
#pragma unroll
            for (int kw = 0; kw < 3; ++kw) {
                int khw = kh * 3 + kw;
#pragma unroll
                for (int nt = 0; nt < 2; ++nt) {
                    int ppos = (wp * 2 + nt + kh) * 18 + m + kw;
                    int sw = (ppos & 7);
                    const ushortT* row = xs + ppos * 64;
                    short8 b0  = *(const short8*)(row + (((0 * 4 + q) ^ sw) << 3));
                    short8 b1f = *(const short8*)(row + (((1 * 4 + q) ^ sw) << 3));
                    acc[0][nt] = __builtin_amdgcn_mfma_f32_16x16x32_bf16(
                        afr[khw][0][0], b0, acc[0][nt], 0, 0, 0);
                    acc[1][nt] = __builtin_amdgcn_mfma_f32_16x16x32_bf16(
                        afr[khw][0][1], b0, acc[1][nt], 0, 0, 0);
                    acc[0][nt] = __builtin_amdgcn_mfma_f32_16x16x32_bf16(
                        afr[khw][1][0], b1f, acc[0][nt], 0, 0, 0);
                    acc[1][nt] = __builtin_amdgcn_mfma_f32_16x16x32_bf16(
                        afr[khw][1][1], b1f, acc[1][nt], 0, 0, 0);
                }
            }
        }
    }

    // store bf16
#pragma unroll
    for (int ot = 0; ot < 2; ++ot) {
#pragma unroll
        for (int nt = 0; nt < 2; ++nt) {
#pragma unroll
            for (int r = 0; r < 4; ++r) {
                int o  = wo * 32 + ot * 16 + q * 4 + r;
                int hh = h0 + wp * 2 + nt;
                y2bf[(((size_t)(b * 64 + o) * 8 + t) * 16 + d) * 256 + hh * 16 + m] =
                    f2bf(acc[ot][nt][r]);
            }
        }
    }

    // fused stats2: wp-waves share channels -> LDS combine, then stripe.
    float ss[2][4], sqv[2][4];
#pragma unroll
    for (int ot = 0; ot < 2; ++ot)
#pragma unroll
        for (int r = 0; r < 4; ++r) {
            float s = 0.f, qv = 0.f;
#pragma unroll
            for (int nt = 0; nt < 2; ++nt) {
                float v = acc[ot][nt][r];
                s += v; qv += v * v;
            }
            ss[ot][r] = s; sqv[ot][r] = qv;
        }
#pragma unroll
    for (int off = 1; off < 16; off <<= 1)
#pragma unroll
        for (int ot = 0; ot < 2; ++ot)
#pragma unroll
            for (int r = 0; r < 4; ++r) {
                ss[ot][r]  += __shfl_xor(ss[ot][r], off);
                sqv[ot][r] += __shfl_xor(sqv[ot][r], off);
            }
    if (m == 0) {
#pragma unroll
        for (int ot = 0; ot < 2; ++ot)
#pragma unroll
            for (int r = 0; r < 4; ++r) {
                int o = wo * 32 + ot * 16 + q * 4 + r;
                atomicAdd(&st2[o], ss[ot][r]);
                atomicAdd(&st2[64 + o], sqv[ot][r]);
            }
    }
    __syncthreads();
    if (tid < 128)
        atomicAdd(stats + (blk & (NSTRIPE - 1)) * STRIDE_ST + 128 + tid, st2[tid]);
}

// ---------------------------------------------------------------------------
// K5: conv1x1 64->256 via MFMA; stages RAW y2bf applying bn2+relu (coef2),
// writes y3 fp32 (d_out). Fused stats3 via striped atomics.
__global__ __launch_bounds__(256) void k_conv3_mfma(const ushortT* __restrict__ y2bf,
                                                    const ushortT* __restrict__ wb3,
                                                    const float* __restrict__ coef2,
                                                    float* __restrict__ stats,
                                                    float* __restrict__ y3) {
    __shared__ __align__(16) ushortT yb[64 * 72];   // [n][c64] stride 72

    int tid = threadIdx.x;
    int blk = blockIdx.x;
    int b  = blk >> 9;
    int n0 = (blk & 511) * 64;

    int lane = tid & 63;
    int wv   = tid >> 6;
    int m    = lane & 15;
    int q    = lane >> 4;

    // stage y2bf: 64 n x 64 c, transposed, bn2+relu inline
    for (int idx = tid; idx < 512; idx += 256) {
        int c = idx >> 3, k = idx & 7;
        float2 cc2 = *(const float2*)(coef2 + 2 * c);
        float a = cc2.x, bs = cc2.y;
        uint4 v = *(const uint4*)(y2bf + ((size_t)(b * 64 + c)) * S_TOT + n0 + k * 8);
        uint32_t va[4] = {v.x, v.y, v.z, v.w};
#pragma unroll
        for (int p = 0; p < 4; ++p) {
            float lo = fmaxf(fmaf(a, bf2f((ushortT)(va[p] & 0xffffu)), bs), 0.f);
            float hi = fmaxf(fmaf(a, bf2f((ushortT)(va[p] >> 16)), bs), 0.f);
            yb[(k * 8 + 2 * p)     * 72 + c] = f2bf(lo);
            yb[(k * 8 + 2 * p + 1) * 72 + c] = f2bf(hi);
        }
    }
    __syncthreads();

    floatx4 acc[4][4];
#pragma unroll
    for (int i = 0; i < 4; ++i)
#pragma unroll
        for (int j = 0; j < 4; ++j) acc[i][j] = (floatx4){0.f, 0.f, 0.f, 0.f};

#pragma unroll
    for (int ks = 0; ks < 2; ++ks) {
        short8 afr[4];
#pragma unroll
        for (int ot = 0; ot < 4; ++ot)
            afr[ot] = *(const short8*)(wb3 +
                (((ks * 4 + q) * 256) + wv * 64 + ot * 16 + m) * 8);
#pragma unroll
        for (int pt = 0; pt < 4; ++pt) {
            short8 bfr = *(const short8*)(yb + (pt * 16 + m) * 72 + ks * 32 + q * 8);
#pragma unroll
            for (int ot = 0; ot < 4; ++ot)
                acc[ot][pt] = __builtin_amdgcn_mfma_f32_16x16x32_bf16(
                    afr[ot], bfr, acc[ot][pt], 0, 0, 0);
        }
    }

    // store fp32
#pragma unroll
    for (int ot = 0; ot < 4; ++ot) {
#pragma unroll
        for (int pt = 0; pt < 4; ++pt) {
#pragma unroll
            for (int r = 0; r < 4; ++r) {
                int o = wv * 64 + ot * 16 + q * 4 + r;
                y3[((size_t)(b * 256 + o)) * S_TOT + n0 + pt * 16 + m] = acc[ot][pt][r];
            }
        }
    }

    // fused stats3: channel o = wv*64+ot*16+q*4+r (waves own disjoint channels)
    float ssum[4][4], ssq[4][4];
#pragma unroll
    for (int ot = 0; ot < 4; ++ot)
#pragma unroll
        for (int r = 0; r < 4; ++r) {
            float s = 0.f, qv = 0.f;
#pragma unroll
            for (int pt = 0; pt < 4; ++pt) {
                float v = acc[ot][pt][r];
                s += v; qv += v * v;
            }
            ssum[ot][r] = s; ssq[ot][r] = qv;
        }
#pragma unroll
    for (int off = 1; off < 16; off <<= 1)
#pragma unroll
        for (int ot = 0; ot < 4; ++ot)
#pragma unroll
            for (int r = 0; r < 4; ++r) {
                ssum[ot][r] += __shfl_xor(ssum[ot][r], off);
                ssq[ot][r]  += __shfl_xor(ssq[ot][r], off);
            }
    if (m == 0) {
        float* st = stats + (blk & (NSTRIPE - 1)) * STRIDE_ST;
#pragma unroll
        for (int ot = 0; ot < 4; ++ot)
#pragma unroll
            for (int r = 0; r < 4; ++r) {
                int o = wv * 64 + ot * 16 + q * 4 + r;
                atomicAdd(st + 256 + o, ssum[ot][r]);
                atomicAdd(st + 512 + o, ssq[ot][r]);
            }
    }
}

// ---------------------------------------------------------------------------
// K7: out = relu(bn3(y3) + x), in place on d_out; stats3 summed from stripes
// with a blockIdx-derived (scalar) channel index.
__global__ __launch_bounds__(256) void k_final(const float* __restrict__ x,
                                               const float* __restrict__ stats,
                                               const float* __restrict__ g,
                                               const float* __restrict__ bb,
                                               float* __restrict__ out) {
    size_t i = ((size_t)blockIdx.x * 256 + threadIdx.x) * 4;
    int o = (int)((blockIdx.x >> 5) & 255);   // scalar: block covers one channel
    float s = 0.f, qv = 0.f;
#pragma unroll
    for (int p = 0; p < NSTRIPE; ++p) {
        s  += stats[p * STRIDE_ST + 256 + o];
        qv += stats[p * STRIDE_ST + 512 + o];
    }
    const float n = 65536.f;
    float mean = s / n;
    float var  = qv / n - mean * mean;
    float a  = g[o] * rsqrtf(var + 1e-5f);
    float bs = bb[o] - mean * a;
    float4 y  = *(float4*)(out + i);
    float4 xv = *(const float4*)(x + i);
    float4 r;
    r.x = fmaxf(a * y.x + bs + xv.x, 0.f);
    r.y = fmaxf(a * y.y + bs + xv.y, 0.f);
    r.z = fmaxf(a * y.z + bs + xv.z, 0.f);
    r.w = fmaxf(a * y.w + bs + xv.w, 0.f);
    *(float4*)(out + i) = r;
}

// ---------------------------------------------------------------------------
extern "C" void kernel_launch(void* const* d_in, const int* in_sizes, int n_in,
                              void* d_out, int out_size, void* d_ws, size_t ws_size,
                              hipStream_t stream) {
    const float* x  = (const float*)d_in[0];
    const float* w1 = (const float*)d_in[1];
    const float* g1 = (const float*)d_in[2];
    const float* b1 = (const float*)d_in[3];
    const float* w2 = (const float*)d_in[4];
    const float* g2 = (const float*)d_in[5];
    const float* b2 = (const float*)d_in[6];
    const float* w3 = (const float*)d_in[7];
    const float* g3 = (const float*)d_in[8];
    const float* b3 = (const float*)d_in[9];

    char* ws = (char*)d_ws;
    ushortT* y1bf = (ushortT*)(ws);                //  8 MiB
    ushortT* y1n  = (ushortT*)(ws + 8388608);      //  8 MiB
    ushortT* y2bf = (ushortT*)(ws + 16777216);     //  8 MiB
    ushortT* wb1  = (ushortT*)(ws + 25165824);     //  32 KiB
    ushortT* wb2  = (ushortT*)(ws + 25198592);     // 648 KiB
    ushortT* wb3  = (ushortT*)(ws + 25862144);     //  32 KiB
    float*   stats = (float*)(ws + 25894912);      // 8*768 floats = 24 KiB
    float*   coef1 = (float*)(ws + 25919488);      // 128 floats
    float*   coef2 = (float*)(ws + 25920000);      // 128 floats
    float* y3 = (float*)d_out;

    // grid covers 364544 weight elems + 6144 stats zeroing = 370688 = 1448*256
    k_prep_w     <<<1448,  256, 0, stream>>>(w1, w2, w3, wb1, wb2, wb3, stats);
    k_conv1_mfma <<<512,   256, 0, stream>>>(x, wb1, y1bf, stats);
    k_coef       <<<1,     256, 0, stream>>>(stats, 0, 64, g1, b1, coef1);
    k_prep       <<<2048,  256, 0, stream>>>(y1bf, coef1, y1n);
    k_conv2_mfma <<<1024,  256, 0, stream>>>(y1n, wb2, stats, y2bf);
    k_coef       <<<1,     256, 0, stream>>>(stats, 128, 64, g2, b2, coef2);
    k_conv3_mfma <<<1024,  256, 0, stream>>>(y2bf, wb3, coef2, stats, y3);
    k_final      <<<16384, 256, 0, stream>>>(x, stats, g3, b3, y3);
}

// Round 6
// 422.739 us; speedup vs baseline: 1.2450x; 1.2450x over previous
//
#include <hip/hip_runtime.h>

// Problem constants: B=2, C=256, planes=64, T=8, D=H=W=16
// spatial per batch S = T*D*H*W = 32768
#define S_TOT 32768

typedef unsigned short ushortT;
typedef __attribute__((ext_vector_type(8))) short short8;
typedef __attribute__((ext_vector_type(4))) float floatx4;

__device__ __forceinline__ ushortT f2bf(float f) {
    unsigned u = __float_as_uint(f);
    u = (u + 0x7fffu + ((u >> 16) & 1u)) >> 16;
    return (ushortT)u;
}
__device__ __forceinline__ float bf2f(ushortT h) {
    return __uint_as_float(((unsigned)h) << 16);
}
// normalize+relu a dword holding two bf16 of one channel, repack to bf16x2
__device__ __forceinline__ uint32_t nrm2(uint32_t u, float a, float bs) {
    float lo = fmaxf(fmaf(a, bf2f((ushortT)(u & 0xffffu)), bs), 0.f);
    float hi = fmaxf(fmaf(a, bf2f((ushortT)(u >> 16)), bs), 0.f);
    return (uint32_t)f2bf(lo) | ((uint32_t)f2bf(hi) << 16);
}

// Striped stats buffer: 8 stripes x 768 floats.
// Within a stripe: sum1[64] @0, sq1[64] @64, sum2[64] @128, sq2[64] @192,
//                  sum3[256] @256, sq3[256] @512.
#define NSTRIPE 8
#define STRIDE_ST 768

// ---------------------------------------------------------------------------
// Prep weights + zero stats stripes.
__global__ __launch_bounds__(256) void k_prep_w(const float* __restrict__ w1,
                                                const float* __restrict__ w2,
                                                const float* __restrict__ w3,
                                                ushortT* __restrict__ wb1,
                                                ushortT* __restrict__ wb2,
                                                ushortT* __restrict__ wb3,
                                                float* __restrict__ stats) {
    int idx = blockIdx.x * 256 + threadIdx.x;
    if (idx < 16384) {
        int e = idx;
        int j = e & 7, o = (e >> 3) & 63, q = (e >> 9) & 3, cc = e >> 11;
        int c = cc * 32 + q * 8 + j;
        wb1[e] = f2bf(w1[o * 256 + c]);
    } else if (idx < 16384 + 331776) {
        int e = idx - 16384;
        int j = e & 7, o = (e >> 3) & 63, cb = (e >> 9) & 7, tap = e >> 12;
        int c = cb * 8 + j;
        wb2[e] = f2bf(w2[((size_t)o * 64 + c) * 81 + tap]);
    } else if (idx < 16384 + 331776 + 16384) {
        int e = idx - 348160;
        int j = e & 7, o = (e >> 3) & 255, g = e >> 11;
        int ks = g >> 2, q = g & 3;
        int c = ks * 32 + q * 8 + j;
        wb3[e] = f2bf(w3[o * 64 + c]);
    } else if (idx < 364544 + NSTRIPE * STRIDE_ST) {
        stats[idx - 364544] = 0.f;
    }
}

// ---------------------------------------------------------------------------
// Collapse stripes -> per-channel (a, bs) coefficients. 1 block, nch threads.
__global__ __launch_bounds__(256) void k_coef(const float* __restrict__ stats,
                                              int off, int nch,
                                              const float* __restrict__ g,
                                              const float* __restrict__ bb,
                                              float* __restrict__ coef) {
    int c = threadIdx.x;
    if (c >= nch) return;
    float s = 0.f, qv = 0.f;
#pragma unroll
    for (int p = 0; p < NSTRIPE; ++p) {
        s  += stats[p * STRIDE_ST + off + c];
        qv += stats[p * STRIDE_ST + off + nch + c];
    }
    const float inv_n = 1.f / 65536.f;
    float mu = s * inv_n, var = qv * inv_n - mu * mu;
    float a  = g[c] * rsqrtf(var + 1e-5f);
    coef[2 * c]     = a;
    coef[2 * c + 1] = bb[c] - mu * a;
}

// ---------------------------------------------------------------------------
// bn1-apply pass: y1n = bf16(relu(a*y1bf + bs)). Separate pass so conv2's
// staging critical path has NO dependent VALU transform.
__global__ __launch_bounds__(256) void k_prep(const ushortT* __restrict__ yin,
                                              const float* __restrict__ coef,
                                              ushortT* __restrict__ yout) {
    size_t i = ((size_t)blockIdx.x * 256 + threadIdx.x) * 8;
    int c = (int)((i >> 15) & 63);
    float2 cf = *(const float2*)(coef + 2 * c);
    uint4 v = *(const uint4*)(yin + i);
    uint4 r;
    r.x = nrm2(v.x, cf.x, cf.y);
    r.y = nrm2(v.y, cf.x, cf.y);
    r.z = nrm2(v.z, cf.x, cf.y);
    r.w = nrm2(v.w, cf.x, cf.y);
    *(uint4*)(yout + i) = r;
}

// ---------------------------------------------------------------------------
// K1: conv1x1 256->64 via MFMA. x fp32 converted to bf16 in staging.
// Grid 1024 (n-chunks of 64) -> 4 blocks/CU for latency hiding (was 512/2).
// Fused: per-channel sum/sq of the fp32 accumulators -> striped atomics.
__global__ __launch_bounds__(256) void k_conv1_mfma(const float* __restrict__ x,
                                                    const ushortT* __restrict__ wb1,
                                                    ushortT* __restrict__ y1bf,
                                                    float* __restrict__ stats) {
    __shared__ __align__(16) ushortT xb[64 * 40];   // [n][c32] stride 40

    int tid = threadIdx.x;
    int blk = blockIdx.x;
    int b  = blk >> 9;
    int n0 = (blk & 511) * 64;

    int lane = tid & 63;
    int wv   = tid >> 6;
    int m    = lane & 15;
    int q    = lane >> 4;

    int c_loc = tid & 31;     // staging channel within chunk
    int ng    = tid >> 5;     // staging n-group (8 groups of 8)

    floatx4 acc[4];
#pragma unroll
    for (int i = 0; i < 4; ++i) acc[i] = (floatx4){0.f, 0.f, 0.f, 0.f};

    for (int cc = 0; cc < 8; ++cc) {
        // A fragment from global (L2-hot): o = wv*16+m, k = q*8+j
        short8 afr = *(const short8*)(wb1 + (((cc * 4 + q) * 64) + wv * 16 + m) * 8);

        __syncthreads();
        // stage B: x[c][n] fp32 -> xb[n][c] bf16 (64 positions x 32 channels)
        {
            int c = cc * 32 + c_loc;
            const float* xp = x + ((size_t)(b * 256 + c)) * S_TOT + n0 + ng * 8;
#pragma unroll
            for (int k = 0; k < 2; ++k) {
                float4 v = *(const float4*)(xp + k * 4);
                int nb = ng * 8 + k * 4;
                xb[(nb + 0) * 40 + c_loc] = f2bf(v.x);
                xb[(nb + 1) * 40 + c_loc] = f2bf(v.y);
                xb[(nb + 2) * 40 + c_loc] = f2bf(v.z);
                xb[(nb + 3) * 40 + c_loc] = f2bf(v.w);
            }
        }
        __syncthreads();

#pragma unroll
        for (int pt = 0; pt < 4; ++pt) {
            short8 bfr = *(const short8*)(xb + (pt * 16 + m) * 40 + q * 8);
            acc[pt] = __builtin_amdgcn_mfma_f32_16x16x32_bf16(afr, bfr, acc[pt], 0, 0, 0);
        }
    }

    // store bf16 (unnormalized)
#pragma unroll
    for (int pt = 0; pt < 4; ++pt) {
#pragma unroll
        for (int r = 0; r < 4; ++r) {
            int o = wv * 16 + q * 4 + r;
            y1bf[((size_t)(b * 64 + o)) * S_TOT + n0 + pt * 16 + m] = f2bf(acc[pt][r]);
        }
    }

    // fused stats1: channel o = wv*16+q*4+r, positions vary over (pt, m)
    float ssum[4] = {0.f, 0.f, 0.f, 0.f}, ssq[4] = {0.f, 0.f, 0.f, 0.f};
#pragma unroll
    for (int pt = 0; pt < 4; ++pt)
#pragma unroll
        for (int r = 0; r < 4; ++r) {
            float v = acc[pt][r];
            ssum[r] += v;
            ssq[r]  += v * v;
        }
#pragma unroll
    for (int off = 1; off < 16; off <<= 1)
#pragma unroll
        for (int r = 0; r < 4; ++r) {
            ssum[r] += __shfl_xor(ssum[r], off);
            ssq[r]  += __shfl_xor(ssq[r], off);
        }
    if (m == 0) {
        float* st = stats + (blk & (NSTRIPE - 1)) * STRIDE_ST;
#pragma unroll
        for (int r = 0; r < 4; ++r) {
            int o = wv * 16 + q * 4 + r;
            atomicAdd(st + o, ssum[r]);
            atomicAdd(st + 64 + o, ssq[r]);
        }
    }
}

// ---------------------------------------------------------------------------
// K3: conv 3x3x3x3, 64->64 as bf16 MFMA implicit GEMM.
// Reads PRE-NORMALIZED y1n. Grid 1024 (4-row h quarters). launch_bounds(256,2)
// -> compiler targets 128 VGPRs (the (256,4) variant forced 64 VGPRs and
// spilled catastrophically: 757MB fetch). At 128 VGPRs 4 blocks/CU still fit
// (16 waves x 128 = pool; LDS 14.3KB x 4 = 57KB). Fused stats2.
__global__ __launch_bounds__(256, 2) void k_conv2_mfma(
        const ushortT* __restrict__ y1n,   // [b][c][t][d][h][w] bf16, normalized
        const ushortT* __restrict__ wb2,   // [tap][cb][o][j] bf16
        float* __restrict__ stats,         // add stats2
        ushortT* __restrict__ y2bf) {
    __shared__ __align__(16) ushortT xs[108 * 64];   // 6 rows x 18 ppos x 64c
    __shared__ float st2[128];

    int tid = threadIdx.x;
    int blk = blockIdx.x;
    int b  = blk >> 9;
    int t  = (blk >> 6) & 7;
    int d  = (blk >> 2) & 15;
    int h0 = (blk & 3) * 4;

    int lane = tid & 63;
    int wv   = tid >> 6;
    int m    = lane & 15;
    int q    = lane >> 4;
    int wp   = wv & 1;     // h-pair: rows wp*2 .. wp*2+1 within the 4
    int wo   = wv >> 1;    // o half: o in [wo*32, wo*32+32)

    int c2      = tid & 31;
    int prbase  = tid >> 5;   // 0..7; rows 0..5 staged

    if (tid < 128) st2[tid] = 0.f;

    floatx4 acc[2][2];     // [ot][nt]
#pragma unroll
    for (int i = 0; i < 2; ++i)
#pragma unroll
        for (int j = 0; j < 2; ++j) acc[i][j] = (floatx4){0.f, 0.f, 0.f, 0.f};

    const size_t cstride = 32768;
    uint32_t* xsd = (uint32_t*)xs;

    for (int ktd = 0; ktd < 9; ++ktd) {
        int kt = ktd / 3, kd = ktd - kt * 3;
        int tt = t + kt - 1;
        int dd = d + kd - 1;
        bool pv = (tt >= 0 && tt < 8 && dd >= 0 && dd < 16);
        if (!pv) continue;   // zero contribution: skip staging AND MFMAs

        // Preload this wave's A fragments for all 9 (kh,kw) taps of this ktd.
        short8 afr[9][2][2];   // [khw][ks][ot]
#pragma unroll
        for (int khw = 0; khw < 9; ++khw) {
            int tap = ktd * 9 + khw;
#pragma unroll
            for (int ks = 0; ks < 2; ++ks)
#pragma unroll
                for (int ot = 0; ot < 2; ++ot) {
                    afr[khw][ks][ot] = *(const short8*)(wb2 +
                        (((size_t)(tap * 8 + ks * 4 + q)) * 64 + wo * 32 + ot * 16 + m) * 8);
                }
        }

        __syncthreads();

        if (prbase < 6) {
            int hin = h0 + prbase - 1;
            uint32_t pack[18];
            if (hin >= 0 && hin < 16) {
                const ushortT* p0 = y1n +
                    (((size_t)(b * 64 + 2 * c2) * 8 + tt) * 16 + dd) * 256 + hin * 16;
                const ushortT* p1 = p0 + cstride;
                uint4 r0 = *(const uint4*)p0;
                uint4 r1 = *(const uint4*)(p0 + 8);
                uint4 s0v = *(const uint4*)p1;
                uint4 s1v = *(const uint4*)(p1 + 8);
                uint32_t ra[8] = {r0.x, r0.y, r0.z, r0.w, r1.x, r1.y, r1.z, r1.w};
                uint32_t sa[8] = {s0v.x, s0v.y, s0v.z, s0v.w, s1v.x, s1v.y, s1v.z, s1v.w};
                pack[0] = 0; pack[17] = 0;
#pragma unroll
                for (int k = 0; k < 8; ++k) {
                    pack[1 + 2 * k] = (ra[k] & 0xffffu) | (sa[k] << 16);
                    pack[2 + 2 * k] = (ra[k] >> 16) | (sa[k] & 0xffff0000u);
                }
            } else {
#pragma unroll
                for (int k = 0; k < 18; ++k) pack[k] = 0;
            }
            int pb = prbase * 18;
#pragma unroll
            for (int k = 0; k < 18; ++k) {
                int ppos = pb + k;
                // dword index within 32-dword row, 16B-chunk swizzled
                xsd[ppos * 32 + ((((c2 >> 2) ^ (ppos & 7)) << 2) | (c2 & 3))] = pack[k];
            }
        }
        __syncthreads();

#pragma unroll
        for (int kh = 0; kh < 3; ++kh) {
#pragma unroll
            for (int kw = 0; kw < 3; ++kw) {
                int khw = kh * 3 + kw;
#pragma unroll
                for (int nt = 0; nt < 2; ++nt) {
                    int ppos = (wp * 2 + nt + kh) * 18 + m + kw;
                    int sw = (ppos & 7);
                    const ushortT* row = xs + ppos * 64;
                    short8 b0  = *(const short8*)(row + (((0 * 4 + q) ^ sw) << 3));
                    short8 b1f = *(const short8*)(row + (((1 * 4 + q) ^ sw) << 3));
                    acc[0][nt] = __builtin_amdgcn_mfma_f32_16x16x32_bf16(
                        afr[khw][0][0], b0, acc[0][nt], 0, 0, 0);
                    acc[1][nt] = __builtin_amdgcn_mfma_f32_16x16x32_bf16(
                        afr[khw][0][1], b0, acc[1][nt], 0, 0, 0);
                    acc[0][nt] = __builtin_amdgcn_mfma_f32_16x16x32_bf16(
                        afr[khw][1][0], b1f, acc[0][nt], 0, 0, 0);
                    acc[1][nt] = __builtin_amdgcn_mfma_f32_16x16x32_bf16(
                        afr[khw][1][1], b1f, acc[1][nt], 0, 0, 0);
                }
            }
        }
    }

    // store bf16
#pragma unroll
    for (int ot = 0; ot < 2; ++ot) {
#pragma unroll
        for (int nt = 0; nt < 2; ++nt) {
#pragma unroll
            for (int r = 0; r < 4; ++r) {
                int o  = wo * 32 + ot * 16 + q * 4 + r;
                int hh = h0 + wp * 2 + nt;
                y2bf[(((size_t)(b * 64 + o) * 8 + t) * 16 + d) * 256 + hh * 16 + m] =
                    f2bf(acc[ot][nt][r]);
            }
        }
    }

    // fused stats2: wp-waves share channels -> LDS combine, then stripe.
    float ss[2][4], sqv[2][4];
#pragma unroll
    for (int ot = 0; ot < 2; ++ot)
#pragma unroll
        for (int r = 0; r < 4; ++r) {
            float s = 0.f, qv = 0.f;
#pragma unroll
            for (int nt = 0; nt < 2; ++nt) {
                float v = acc[ot][nt][r];
                s += v; qv += v * v;
            }
            ss[ot][r] = s; sqv[ot][r] = qv;
        }
#pragma unroll
    for (int off = 1; off < 16; off <<= 1)
#pragma unroll
        for (int ot = 0; ot < 2; ++ot)
#pragma unroll
            for (int r = 0; r < 4; ++r) {
                ss[ot][r]  += __shfl_xor(ss[ot][r], off);
                sqv[ot][r] += __shfl_xor(sqv[ot][r], off);
            }
    if (m == 0) {
#pragma unroll
        for (int ot = 0; ot < 2; ++ot)
#pragma unroll
            for (int r = 0; r < 4; ++r) {
                int o = wo * 32 + ot * 16 + q * 4 + r;
                atomicAdd(&st2[o], ss[ot][r]);
                atomicAdd(&st2[64 + o], sqv[ot][r]);
            }
    }
    __syncthreads();
    if (tid < 128)
        atomicAdd(stats + (blk & (NSTRIPE - 1)) * STRIDE_ST + 128 + tid, st2[tid]);
}

// ---------------------------------------------------------------------------
// K5: conv1x1 64->256 via MFMA; stages RAW y2bf applying bn2+relu (coef2),
// writes y3 fp32 (d_out). Fused stats3 via striped atomics.
__global__ __launch_bounds__(256) void k_conv3_mfma(const ushortT* __restrict__ y2bf,
                                                    const ushortT* __restrict__ wb3,
                                                    const float* __restrict__ coef2,
                                                    float* __restrict__ stats,
                                                    float* __restrict__ y3) {
    __shared__ __align__(16) ushortT yb[64 * 72];   // [n][c64] stride 72

    int tid = threadIdx.x;
    int blk = blockIdx.x;
    int b  = blk >> 9;
    int n0 = (blk & 511) * 64;

    int lane = tid & 63;
    int wv   = tid >> 6;
    int m    = lane & 15;
    int q    = lane >> 4;

    // stage y2bf: 64 n x 64 c, transposed, bn2+relu inline
    for (int idx = tid; idx < 512; idx += 256) {
        int c = idx >> 3, k = idx & 7;
        float2 cc2 = *(const float2*)(coef2 + 2 * c);
        float a = cc2.x, bs = cc2.y;
        uint4 v = *(const uint4*)(y2bf + ((size_t)(b * 64 + c)) * S_TOT + n0 + k * 8);
        uint32_t va[4] = {v.x, v.y, v.z, v.w};
#pragma unroll
        for (int p = 0; p < 4; ++p) {
            float lo = fmaxf(fmaf(a, bf2f((ushortT)(va[p] & 0xffffu)), bs), 0.f);
            float hi = fmaxf(fmaf(a, bf2f((ushortT)(va[p] >> 16)), bs), 0.f);
            yb[(k * 8 + 2 * p)     * 72 + c] = f2bf(lo);
            yb[(k * 8 + 2 * p + 1) * 72 + c] = f2bf(hi);
        }
    }
    __syncthreads();

    floatx4 acc[4][4];
#pragma unroll
    for (int i = 0; i < 4; ++i)
#pragma unroll
        for (int j = 0; j < 4; ++j) acc[i][j] = (floatx4){0.f, 0.f, 0.f, 0.f};

#pragma unroll
    for (int ks = 0; ks < 2; ++ks) {
        short8 afr[4];
#pragma unroll
        for (int ot = 0; ot < 4; ++ot)
            afr[ot] = *(const short8*)(wb3 +
                (((ks * 4 + q) * 256) + wv * 64 + ot * 16 + m) * 8);
#pragma unroll
        for (int pt = 0; pt < 4; ++pt) {
            short8 bfr = *(const short8*)(yb + (pt * 16 + m) * 72 + ks * 32 + q * 8);
#pragma unroll
            for (int ot = 0; ot < 4; ++ot)
                acc[ot][pt] = __builtin_amdgcn_mfma_f32_16x16x32_bf16(
                    afr[ot], bfr, acc[ot][pt], 0, 0, 0);
        }
    }

    // store fp32
#pragma unroll
    for (int ot = 0; ot < 4; ++ot) {
#pragma unroll
        for (int pt = 0; pt < 4; ++pt) {
#pragma unroll
            for (int r = 0; r < 4; ++r) {
                int o = wv * 64 + ot * 16 + q * 4 + r;
                y3[((size_t)(b * 256 + o)) * S_TOT + n0 + pt * 16 + m] = acc[ot][pt][r];
            }
        }
    }

    // fused stats3: channel o = wv*64+ot*16+q*4+r (waves own disjoint channels)
    float ssum[4][4], ssq[4][4];
#pragma unroll
    for (int ot = 0; ot < 4; ++ot)
#pragma unroll
        for (int r = 0; r < 4; ++r) {
            float s = 0.f, qv = 0.f;
#pragma unroll
            for (int pt = 0; pt < 4; ++pt) {
                float v = acc[ot][pt][r];
                s += v; qv += v * v;
            }
            ssum[ot][r] = s; ssq[ot][r] = qv;
        }
#pragma unroll
    for (int off = 1; off < 16; off <<= 1)
#pragma unroll
        for (int ot = 0; ot < 4; ++ot)
#pragma unroll
            for (int r = 0; r < 4; ++r) {
                ssum[ot][r] += __shfl_xor(ssum[ot][r], off);
                ssq[ot][r]  += __shfl_xor(ssq[ot][r], off);
            }
    if (m == 0) {
        float* st = stats + (blk & (NSTRIPE - 1)) * STRIDE_ST;
#pragma unroll
        for (int ot = 0; ot < 4; ++ot)
#pragma unroll
            for (int r = 0; r < 4; ++r) {
                int o = wv * 64 + ot * 16 + q * 4 + r;
                atomicAdd(st + 256 + o, ssum[ot][r]);
                atomicAdd(st + 512 + o, ssq[ot][r]);
            }
    }
}

// ---------------------------------------------------------------------------
// K7: out = relu(bn3(y3) + x), in place on d_out; stats3 summed from stripes
// with a blockIdx-derived (scalar) channel index.
__global__ __launch_bounds__(256) void k_final(const float* __restrict__ x,
                                               const float* __restrict__ stats,
                                               const float* __restrict__ g,
                                               const float* __restrict__ bb,
                                               float* __restrict__ out) {
    size_t i = ((size_t)blockIdx.x * 256 + threadIdx.x) * 4;
    int o = (int)((blockIdx.x >> 5) & 255);   // scalar: block covers one channel
    float s = 0.f, qv = 0.f;
#pragma unroll
    for (int p = 0; p < NSTRIPE; ++p) {
        s  += stats[p * STRIDE_ST + 256 + o];
        qv += stats[p * STRIDE_ST + 512 + o];
    }
    const float n = 65536.f;
    float mean = s / n;
    float var  = qv / n - mean * mean;
    float a  = g[o] * rsqrtf(var + 1e-5f);
    float bs = bb[o] - mean * a;
    float4 y  = *(float4*)(out + i);
    float4 xv = *(const float4*)(x + i);
    float4 r;
    r.x = fmaxf(a * y.x + bs + xv.x, 0.f);
    r.y = fmaxf(a * y.y + bs + xv.y, 0.f);
    r.z = fmaxf(a * y.z + bs + xv.z, 0.f);
    r.w = fmaxf(a * y.w + bs + xv.w, 0.f);
    *(float4*)(out + i) = r;
}

// ---------------------------------------------------------------------------
extern "C" void kernel_launch(void* const* d_in, const int* in_sizes, int n_in,
                              void* d_out, int out_size, void* d_ws, size_t ws_size,
                              hipStream_t stream) {
    const float* x  = (const float*)d_in[0];
    const float* w1 = (const float*)d_in[1];
    const float* g1 = (const float*)d_in[2];
    const float* b1 = (const float*)d_in[3];
    const float* w2 = (const float*)d_in[4];
    const float* g2 = (const float*)d_in[5];
    const float* b2 = (const float*)d_in[6];
    const float* w3 = (const float*)d_in[7];
    const float* g3 = (const float*)d_in[8];
    const float* b3 = (const float*)d_in[9];

    char* ws = (char*)d_ws;
    ushortT* y1bf = (ushortT*)(ws);                //  8 MiB
    ushortT* y1n  = (ushortT*)(ws + 8388608);      //  8 MiB
    ushortT* y2bf = (ushortT*)(ws + 16777216);     //  8 MiB
    ushortT* wb1  = (ushortT*)(ws + 25165824);     //  32 KiB
    ushortT* wb2  = (ushortT*)(ws + 25198592);     // 648 KiB
    ushortT* wb3  = (ushortT*)(ws + 25862144);     //  32 KiB
    float*   stats = (float*)(ws + 25894912);      // 8*768 floats = 24 KiB
    float*   coef1 = (float*)(ws + 25919488);      // 128 floats
    float*   coef2 = (float*)(ws + 25920000);      // 128 floats
    float* y3 = (float*)d_out;

    // grid covers 364544 weight elems + 6144 stats zeroing = 370688 = 1448*256
    k_prep_w     <<<1448,  256, 0, stream>>>(w1, w2, w3, wb1, wb2, wb3, stats);
    k_conv1_mfma <<<1024,  256, 0, stream>>>(x, wb1, y1bf, stats);
    k_coef       <<<1,     256, 0, stream>>>(stats, 0, 64, g1, b1, coef1);
    k_prep       <<<2048,  256, 0, stream>>>(y1bf, coef1, y1n);
    k_conv2_mfma <<<1024,  256, 0, stream>>>(y1n, wb2, stats, y2bf);
    k_coef       <<<1,     256, 0, stream>>>(stats, 128, 64, g2, b2, coef2);
    k_conv3_mfma <<<1024,  256, 0, stream>>>(y2bf, wb3, coef2, stats, y3);
    k_final      <<<16384, 256, 0, stream>>>(x, stats, g3, b3, y3);
}

// Round 7
// 253.425 us; speedup vs baseline: 2.0768x; 1.6681x over previous
//
#include <hip/hip_runtime.h>

// Problem constants: B=2, C=256, planes=64, T=8, D=H=W=16
// spatial per batch S = T*D*H*W = 32768
#define S_TOT 32768

typedef unsigned short ushortT;
typedef __attribute__((ext_vector_type(8))) short short8;
typedef __attribute__((ext_vector_type(4))) float floatx4;

__device__ __forceinline__ ushortT f2bf(float f) {
    unsigned u = __float_as_uint(f);
    u = (u + 0x7fffu + ((u >> 16) & 1u)) >> 16;
    return (ushortT)u;
}
__device__ __forceinline__ float bf2f(ushortT h) {
    return __uint_as_float(((unsigned)h) << 16);
}
// normalize+relu a dword holding two bf16 of one channel, repack to bf16x2
__device__ __forceinline__ uint32_t nrm2(uint32_t u, float a, float bs) {
    float lo = fmaxf(fmaf(a, bf2f((ushortT)(u & 0xffffu)), bs), 0.f);
    float hi = fmaxf(fmaf(a, bf2f((ushortT)(u >> 16)), bs), 0.f);
    return (uint32_t)f2bf(lo) | ((uint32_t)f2bf(hi) << 16);
}

// Striped stats buffer: 8 stripes x 768 floats.
// Within a stripe: sum1[64] @0, sq1[64] @64, sum2[64] @128, sq2[64] @192,
//                  sum3[256] @256, sq3[256] @512.
#define NSTRIPE 8
#define STRIDE_ST 768

// ---------------------------------------------------------------------------
// Prep weights + zero stats stripes.
__global__ __launch_bounds__(256) void k_prep_w(const float* __restrict__ w1,
                                                const float* __restrict__ w2,
                                                const float* __restrict__ w3,
                                                ushortT* __restrict__ wb1,
                                                ushortT* __restrict__ wb2,
                                                ushortT* __restrict__ wb3,
                                                float* __restrict__ stats) {
    int idx = blockIdx.x * 256 + threadIdx.x;
    if (idx < 16384) {
        int e = idx;
        int j = e & 7, o = (e >> 3) & 63, q = (e >> 9) & 3, cc = e >> 11;
        int c = cc * 32 + q * 8 + j;
        wb1[e] = f2bf(w1[o * 256 + c]);
    } else if (idx < 16384 + 331776) {
        int e = idx - 16384;
        int j = e & 7, o = (e >> 3) & 63, cb = (e >> 9) & 7, tap = e >> 12;
        int c = cb * 8 + j;
        wb2[e] = f2bf(w2[((size_t)o * 64 + c) * 81 + tap]);
    } else if (idx < 16384 + 331776 + 16384) {
        int e = idx - 348160;
        int j = e & 7, o = (e >> 3) & 255, g = e >> 11;
        int ks = g >> 2, q = g & 3;
        int c = ks * 32 + q * 8 + j;
        wb3[e] = f2bf(w3[o * 64 + c]);
    } else if (idx < 364544 + NSTRIPE * STRIDE_ST) {
        stats[idx - 364544] = 0.f;
    }
}

// ---------------------------------------------------------------------------
// Collapse stripes -> per-channel (a, bs) coefficients. 1 block, nch threads.
__global__ __launch_bounds__(256) void k_coef(const float* __restrict__ stats,
                                              int off, int nch,
                                              const float* __restrict__ g,
                                              const float* __restrict__ bb,
                                              float* __restrict__ coef) {
    int c = threadIdx.x;
    if (c >= nch) return;
    float s = 0.f, qv = 0.f;
#pragma unroll
    for (int p = 0; p < NSTRIPE; ++p) {
        s  += stats[p * STRIDE_ST + off + c];
        qv += stats[p * STRIDE_ST + off + nch + c];
    }
    const float inv_n = 1.f / 65536.f;
    float mu = s * inv_n, var = qv * inv_n - mu * mu;
    float a  = g[c] * rsqrtf(var + 1e-5f);
    coef[2 * c]     = a;
    coef[2 * c + 1] = bb[c] - mu * a;
}

// ---------------------------------------------------------------------------
// bn1-apply pass: y1n = bf16(relu(a*y1bf + bs)). Separate pass so conv2's
// staging critical path has NO dependent VALU transform.
__global__ __launch_bounds__(256) void k_prep(const ushortT* __restrict__ yin,
                                              const float* __restrict__ coef,
                                              ushortT* __restrict__ yout) {
    size_t i = ((size_t)blockIdx.x * 256 + threadIdx.x) * 8;
    int c = (int)((i >> 15) & 63);
    float2 cf = *(const float2*)(coef + 2 * c);
    uint4 v = *(const uint4*)(yin + i);
    uint4 r;
    r.x = nrm2(v.x, cf.x, cf.y);
    r.y = nrm2(v.y, cf.x, cf.y);
    r.z = nrm2(v.z, cf.x, cf.y);
    r.w = nrm2(v.w, cf.x, cf.y);
    *(uint4*)(yout + i) = r;
}

// ---------------------------------------------------------------------------
// K1: conv1x1 256->64 via MFMA. x fp32 converted to bf16 in staging.
// Grid 1024 (n-chunks of 64) -> 4 blocks/CU for latency hiding.
// Fused: per-channel sum/sq of the fp32 accumulators -> striped atomics.
__global__ __launch_bounds__(256) void k_conv1_mfma(const float* __restrict__ x,
                                                    const ushortT* __restrict__ wb1,
                                                    ushortT* __restrict__ y1bf,
                                                    float* __restrict__ stats) {
    __shared__ __align__(16) ushortT xb[64 * 40];   // [n][c32] stride 40

    int tid = threadIdx.x;
    int blk = blockIdx.x;
    int b  = blk >> 9;
    int n0 = (blk & 511) * 64;

    int lane = tid & 63;
    int wv   = tid >> 6;
    int m    = lane & 15;
    int q    = lane >> 4;

    int c_loc = tid & 31;     // staging channel within chunk
    int ng    = tid >> 5;     // staging n-group (8 groups of 8)

    floatx4 acc[4];
#pragma unroll
    for (int i = 0; i < 4; ++i) acc[i] = (floatx4){0.f, 0.f, 0.f, 0.f};

    for (int cc = 0; cc < 8; ++cc) {
        // A fragment from global (L2-hot): o = wv*16+m, k = q*8+j
        short8 afr = *(const short8*)(wb1 + (((cc * 4 + q) * 64) + wv * 16 + m) * 8);

        __syncthreads();
        // stage B: x[c][n] fp32 -> xb[n][c] bf16 (64 positions x 32 channels)
        {
            int c = cc * 32 + c_loc;
            const float* xp = x + ((size_t)(b * 256 + c)) * S_TOT + n0 + ng * 8;
#pragma unroll
            for (int k = 0; k < 2; ++k) {
                float4 v = *(const float4*)(xp + k * 4);
                int nb = ng * 8 + k * 4;
                xb[(nb + 0) * 40 + c_loc] = f2bf(v.x);
                xb[(nb + 1) * 40 + c_loc] = f2bf(v.y);
                xb[(nb + 2) * 40 + c_loc] = f2bf(v.z);
                xb[(nb + 3) * 40 + c_loc] = f2bf(v.w);
            }
        }
        __syncthreads();

#pragma unroll
        for (int pt = 0; pt < 4; ++pt) {
            short8 bfr = *(const short8*)(xb + (pt * 16 + m) * 40 + q * 8);
            acc[pt] = __builtin_amdgcn_mfma_f32_16x16x32_bf16(afr, bfr, acc[pt], 0, 0, 0);
        }
    }

    // store bf16 (unnormalized)
#pragma unroll
    for (int pt = 0; pt < 4; ++pt) {
#pragma unroll
        for (int r = 0; r < 4; ++r) {
            int o = wv * 16 + q * 4 + r;
            y1bf[((size_t)(b * 64 + o)) * S_TOT + n0 + pt * 16 + m] = f2bf(acc[pt][r]);
        }
    }

    // fused stats1: channel o = wv*16+q*4+r, positions vary over (pt, m)
    float ssum[4] = {0.f, 0.f, 0.f, 0.f}, ssq[4] = {0.f, 0.f, 0.f, 0.f};
#pragma unroll
    for (int pt = 0; pt < 4; ++pt)
#pragma unroll
        for (int r = 0; r < 4; ++r) {
            float v = acc[pt][r];
            ssum[r] += v;
            ssq[r]  += v * v;
        }
#pragma unroll
    for (int off = 1; off < 16; off <<= 1)
#pragma unroll
        for (int r = 0; r < 4; ++r) {
            ssum[r] += __shfl_xor(ssum[r], off);
            ssq[r]  += __shfl_xor(ssq[r], off);
        }
    if (m == 0) {
        float* st = stats + (blk & (NSTRIPE - 1)) * STRIDE_ST;
#pragma unroll
        for (int r = 0; r < 4; ++r) {
            int o = wv * 16 + q * 4 + r;
            atomicAdd(st + o, ssum[r]);
            atomicAdd(st + 64 + o, ssq[r]);
        }
    }
}

// ---------------------------------------------------------------------------
// K3: conv 3x3x3x3, 64->64 as bf16 MFMA implicit GEMM.
// Reads PRE-NORMALIZED y1n. Grid 1024 (4-row h quarters).
// REGISTER-LIGHT weight streaming: instead of preloading all 36 fragments of
// a plane (144 VGPRs live across barriers -> allocator spilled 50MB+ in every
// prior variant), fragments for each khw are double-buffered: the 4 fragments
// (2ks x 2ot, 32 VGPRs max live) for khw+1 load from L2-hot wb2 while khw's
// 8 MFMAs run. Compiler fence per khw stops re-hoisting. Fused stats2.
__global__ __launch_bounds__(256, 2) void k_conv2_mfma(
        const ushortT* __restrict__ y1n,   // [b][c][t][d][h][w] bf16, normalized
        const ushortT* __restrict__ wb2,   // [tap][cb][o][j] bf16
        float* __restrict__ stats,         // add stats2
        ushortT* __restrict__ y2bf) {
    __shared__ __align__(16) ushortT xs[108 * 64];   // 6 rows x 18 ppos x 64c
    __shared__ float st2[128];

    int tid = threadIdx.x;
    int blk = blockIdx.x;
    int b  = blk >> 9;
    int t  = (blk >> 6) & 7;
    int d  = (blk >> 2) & 15;
    int h0 = (blk & 3) * 4;

    int lane = tid & 63;
    int wv   = tid >> 6;
    int m    = lane & 15;
    int q    = lane >> 4;
    int wp   = wv & 1;     // h-pair: rows wp*2 .. wp*2+1 within the 4
    int wo   = wv >> 1;    // o half: o in [wo*32, wo*32+32)

    int c2      = tid & 31;
    int prbase  = tid >> 5;   // 0..7; rows 0..5 staged

    if (tid < 128) st2[tid] = 0.f;

    // per-wave weight fragment base: (tap,ks,ot) -> wb2 offset
    const ushortT* wfb = wb2 + ((size_t)q * 64 + wo * 32 + m) * 8;
    // addr(tap, ks, ot) = wfb + ((tap*8 + ks*4)*64 + ot*16) * 8

    floatx4 acc[2][2];     // [ot][nt]
#pragma unroll
    for (int i = 0; i < 2; ++i)
#pragma unroll
        for (int j = 0; j < 2; ++j) acc[i][j] = (floatx4){0.f, 0.f, 0.f, 0.f};

    const size_t cstride = 32768;
    uint32_t* xsd = (uint32_t*)xs;

    for (int ktd = 0; ktd < 9; ++ktd) {
        int kt = ktd / 3, kd = ktd - kt * 3;
        int tt = t + kt - 1;
        int dd = d + kd - 1;
        bool pv = (tt >= 0 && tt < 8 && dd >= 0 && dd < 16);
        if (!pv) continue;   // zero contribution: skip staging AND MFMAs

        __syncthreads();   // previous plane's MFMA reads done

        if (prbase < 6) {
            int hin = h0 + prbase - 1;
            uint32_t pack[18];
            if (hin >= 0 && hin < 16) {
                const ushortT* p0 = y1n +
                    (((size_t)(b * 64 + 2 * c2) * 8 + tt) * 16 + dd) * 256 + hin * 16;
                const ushortT* p1 = p0 + cstride;
                uint4 r0 = *(const uint4*)p0;
                uint4 r1 = *(const uint4*)(p0 + 8);
                uint4 s0v = *(const uint4*)p1;
                uint4 s1v = *(const uint4*)(p1 + 8);
                uint32_t ra[8] = {r0.x, r0.y, r0.z, r0.w, r1.x, r1.y, r1.z, r1.w};
                uint32_t sa[8] = {s0v.x, s0v.y, s0v.z, s0v.w, s1v.x, s1v.y, s1v.z, s1v.w};
                pack[0] = 0; pack[17] = 0;
#pragma unroll
                for (int k = 0; k < 8; ++k) {
                    pack[1 + 2 * k] = (ra[k] & 0xffffu) | (sa[k] << 16);
                    pack[2 + 2 * k] = (ra[k] >> 16) | (sa[k] & 0xffff0000u);
                }
            } else {
#pragma unroll
                for (int k = 0; k < 18; ++k) pack[k] = 0;
            }
            int pb = prbase * 18;
#pragma unroll
            for (int k = 0; k < 18; ++k) {
                int ppos = pb + k;
                // dword index within 32-dword row, 16B-chunk swizzled
                xsd[ppos * 32 + ((((c2 >> 2) ^ (ppos & 7)) << 2) | (c2 & 3))] = pack[k];
            }
        }

        // issue khw=0 fragment loads before the barrier (fly during the wait)
        int tap0 = ktd * 9;
        short8 c00 = *(const short8*)(wfb + ((size_t)(tap0 * 8) * 64) * 8);
        short8 c01 = *(const short8*)(wfb + ((size_t)(tap0 * 8) * 64 + 16) * 8);
        short8 c10 = *(const short8*)(wfb + ((size_t)(tap0 * 8 + 4) * 64) * 8);
        short8 c11 = *(const short8*)(wfb + ((size_t)(tap0 * 8 + 4) * 64 + 16) * 8);

        __syncthreads();   // LDS ready

#pragma unroll
        for (int khw = 0; khw < 9; ++khw) {
            // prefetch next khw's fragments (L2-hot) under this khw's MFMAs
            short8 n00, n01, n10, n11;
            if (khw < 8) {
                int tap = tap0 + khw + 1;
                n00 = *(const short8*)(wfb + ((size_t)(tap * 8) * 64) * 8);
                n01 = *(const short8*)(wfb + ((size_t)(tap * 8) * 64 + 16) * 8);
                n10 = *(const short8*)(wfb + ((size_t)(tap * 8 + 4) * 64) * 8);
                n11 = *(const short8*)(wfb + ((size_t)(tap * 8 + 4) * 64 + 16) * 8);
            }
            int kh = khw / 3, kw = khw - kh * 3;
#pragma unroll
            for (int nt = 0; nt < 2; ++nt) {
                int ppos = (wp * 2 + nt + kh) * 18 + m + kw;
                int sw = (ppos & 7);
                const ushortT* row = xs + ppos * 64;
                short8 b0  = *(const short8*)(row + (((0 * 4 + q) ^ sw) << 3));
                short8 b1f = *(const short8*)(row + (((1 * 4 + q) ^ sw) << 3));
                acc[0][nt] = __builtin_amdgcn_mfma_f32_16x16x32_bf16(
                    c00, b0, acc[0][nt], 0, 0, 0);
                acc[1][nt] = __builtin_amdgcn_mfma_f32_16x16x32_bf16(
                    c01, b0, acc[1][nt], 0, 0, 0);
                acc[0][nt] = __builtin_amdgcn_mfma_f32_16x16x32_bf16(
                    c10, b1f, acc[0][nt], 0, 0, 0);
                acc[1][nt] = __builtin_amdgcn_mfma_f32_16x16x32_bf16(
                    c11, b1f, acc[1][nt], 0, 0, 0);
            }
            c00 = n00; c01 = n01; c10 = n10; c11 = n11;
            // stop the scheduler from hoisting later iterations' loads up
            // (bounded register liveness; the spill was 2.5-6x before)
            asm volatile("" ::: "memory");
        }
    }

    // store bf16
#pragma unroll
    for (int ot = 0; ot < 2; ++ot) {
#pragma unroll
        for (int nt = 0; nt < 2; ++nt) {
#pragma unroll
            for (int r = 0; r < 4; ++r) {
                int o  = wo * 32 + ot * 16 + q * 4 + r;
                int hh = h0 + wp * 2 + nt;
                y2bf[(((size_t)(b * 64 + o) * 8 + t) * 16 + d) * 256 + hh * 16 + m] =
                    f2bf(acc[ot][nt][r]);
            }
        }
    }

    // fused stats2: wp-waves share channels -> LDS combine, then stripe.
    float ss[2][4], sqv[2][4];
#pragma unroll
    for (int ot = 0; ot < 2; ++ot)
#pragma unroll
        for (int r = 0; r < 4; ++r) {
            float s = 0.f, qv = 0.f;
#pragma unroll
            for (int nt = 0; nt < 2; ++nt) {
                float v = acc[ot][nt][r];
                s += v; qv += v * v;
            }
            ss[ot][r] = s; sqv[ot][r] = qv;
        }
#pragma unroll
    for (int off = 1; off < 16; off <<= 1)
#pragma unroll
        for (int ot = 0; ot < 2; ++ot)
#pragma unroll
            for (int r = 0; r < 4; ++r) {
                ss[ot][r]  += __shfl_xor(ss[ot][r], off);
                sqv[ot][r] += __shfl_xor(sqv[ot][r], off);
            }
    if (m == 0) {
#pragma unroll
        for (int ot = 0; ot < 2; ++ot)
#pragma unroll
            for (int r = 0; r < 4; ++r) {
                int o = wo * 32 + ot * 16 + q * 4 + r;
                atomicAdd(&st2[o], ss[ot][r]);
                atomicAdd(&st2[64 + o], sqv[ot][r]);
            }
    }
    __syncthreads();
    if (tid < 128)
        atomicAdd(stats + (blk & (NSTRIPE - 1)) * STRIDE_ST + 128 + tid, st2[tid]);
}

// ---------------------------------------------------------------------------
// K5: conv1x1 64->256 via MFMA; stages RAW y2bf applying bn2+relu (coef2),
// writes y3 fp32 (d_out). Fused stats3 via striped atomics.
__global__ __launch_bounds__(256) void k_conv3_mfma(const ushortT* __restrict__ y2bf,
                                                    const ushortT* __restrict__ wb3,
                                                    const float* __restrict__ coef2,
                                                    float* __restrict__ stats,
                                                    float* __restrict__ y3) {
    __shared__ __align__(16) ushortT yb[64 * 72];   // [n][c64] stride 72

    int tid = threadIdx.x;
    int blk = blockIdx.x;
    int b  = blk >> 9;
    int n0 = (blk & 511) * 64;

    int lane = tid & 63;
    int wv   = tid >> 6;
    int m    = lane & 15;
    int q    = lane >> 4;

    // stage y2bf: 64 n x 64 c, transposed, bn2+relu inline
    for (int idx = tid; idx < 512; idx += 256) {
        int c = idx >> 3, k = idx & 7;
        float2 cc2 = *(const float2*)(coef2 + 2 * c);
        float a = cc2.x, bs = cc2.y;
        uint4 v = *(const uint4*)(y2bf + ((size_t)(b * 64 + c)) * S_TOT + n0 + k * 8);
        uint32_t va[4] = {v.x, v.y, v.z, v.w};
#pragma unroll
        for (int p = 0; p < 4; ++p) {
            float lo = fmaxf(fmaf(a, bf2f((ushortT)(va[p] & 0xffffu)), bs), 0.f);
            float hi = fmaxf(fmaf(a, bf2f((ushortT)(va[p] >> 16)), bs), 0.f);
            yb[(k * 8 + 2 * p)     * 72 + c] = f2bf(lo);
            yb[(k * 8 + 2 * p + 1) * 72 + c] = f2bf(hi);
        }
    }
    __syncthreads();

    floatx4 acc[4][4];
#pragma unroll
    for (int i = 0; i < 4; ++i)
#pragma unroll
        for (int j = 0; j < 4; ++j) acc[i][j] = (floatx4){0.f, 0.f, 0.f, 0.f};

#pragma unroll
    for (int ks = 0; ks < 2; ++ks) {
        short8 afr[4];
#pragma unroll
        for (int ot = 0; ot < 4; ++ot)
            afr[ot] = *(const short8*)(wb3 +
                (((ks * 4 + q) * 256) + wv * 64 + ot * 16 + m) * 8);
#pragma unroll
        for (int pt = 0; pt < 4; ++pt) {
            short8 bfr = *(const short8*)(yb + (pt * 16 + m) * 72 + ks * 32 + q * 8);
#pragma unroll
            for (int ot = 0; ot < 4; ++ot)
                acc[ot][pt] = __builtin_amdgcn_mfma_f32_16x16x32_bf16(
                    afr[ot], bfr, acc[ot][pt], 0, 0, 0);
        }
    }

    // store fp32
#pragma unroll
    for (int ot = 0; ot < 4; ++ot) {
#pragma unroll
        for (int pt = 0; pt < 4; ++pt) {
#pragma unroll
            for (int r = 0; r < 4; ++r) {
                int o = wv * 64 + ot * 16 + q * 4 + r;
                y3[((size_t)(b * 256 + o)) * S_TOT + n0 + pt * 16 + m] = acc[ot][pt][r];
            }
        }
    }

    // fused stats3: channel o = wv*64+ot*16+q*4+r (waves own disjoint channels)
    float ssum[4][4], ssq[4][4];
#pragma unroll
    for (int ot = 0; ot < 4; ++ot)
#pragma unroll
        for (int r = 0; r < 4; ++r) {
            float s = 0.f, qv = 0.f;
#pragma unroll
            for (int pt = 0; pt < 4; ++pt) {
                float v = acc[ot][pt][r];
                s += v; qv += v * v;
            }
            ssum[ot][r] = s; ssq[ot][r] = qv;
        }
#pragma unroll
    for (int off = 1; off < 16; off <<= 1)
#pragma unroll
        for (int ot = 0; ot < 4; ++ot)
#pragma unroll
            for (int r = 0; r < 4; ++r) {
                ssum[ot][r] += __shfl_xor(ssum[ot][r], off);
                ssq[ot][r]  += __shfl_xor(ssq[ot][r], off);
            }
    if (m == 0) {
        float* st = stats + (blk & (NSTRIPE - 1)) * STRIDE_ST;
#pragma unroll
        for (int ot = 0; ot < 4; ++ot)
#pragma unroll
            for (int r = 0; r < 4; ++r) {
                int o = wv * 64 + ot * 16 + q * 4 + r;
                atomicAdd(st + 256 + o, ssum[ot][r]);
                atomicAdd(st + 512 + o, ssq[ot][r]);
            }
    }
}

// ---------------------------------------------------------------------------
// K7: out = relu(bn3(y3) + x), in place on d_out; stats3 summed from stripes
// with a blockIdx-derived (scalar) channel index.
__global__ __launch_bounds__(256) void k_final(const float* __restrict__ x,
                                               const float* __restrict__ stats,
                                               const float* __restrict__ g,
                                               const float* __restrict__ bb,
                                               float* __restrict__ out) {
    size_t i = ((size_t)blockIdx.x * 256 + threadIdx.x) * 4;
    int o = (int)((blockIdx.x >> 5) & 255);   // scalar: block covers one channel
    float s = 0.f, qv = 0.f;
#pragma unroll
    for (int p = 0; p < NSTRIPE; ++p) {
        s  += stats[p * STRIDE_ST + 256 + o];
        qv += stats[p * STRIDE_ST + 512 + o];
    }
    const float n = 65536.f;
    float mean = s / n;
    float var  = qv / n - mean * mean;
    float a  = g[o] * rsqrtf(var + 1e-5f);
    float bs = bb[o] - mean * a;
    float4 y  = *(float4*)(out + i);
    float4 xv = *(const float4*)(x + i);
    float4 r;
    r.x = fmaxf(a * y.x + bs + xv.x, 0.f);
    r.y = fmaxf(a * y.y + bs + xv.y, 0.f);
    r.z = fmaxf(a * y.z + bs + xv.z, 0.f);
    r.w = fmaxf(a * y.w + bs + xv.w, 0.f);
    *(float4*)(out + i) = r;
}

// ---------------------------------------------------------------------------
extern "C" void kernel_launch(void* const* d_in, const int* in_sizes, int n_in,
                              void* d_out, int out_size, void* d_ws, size_t ws_size,
                              hipStream_t stream) {
    const float* x  = (const float*)d_in[0];
    const float* w1 = (const float*)d_in[1];
    const float* g1 = (const float*)d_in[2];
    const float* b1 = (const float*)d_in[3];
    const float* w2 = (const float*)d_in[4];
    const float* g2 = (const float*)d_in[5];
    const float* b2 = (const float*)d_in[6];
    const float* w3 = (const float*)d_in[7];
    const float* g3 = (const float*)d_in[8];
    const float* b3 = (const float*)d_in[9];

    char* ws = (char*)d_ws;
    ushortT* y1bf = (ushortT*)(ws);                //  8 MiB
    ushortT* y1n  = (ushortT*)(ws + 8388608);      //  8 MiB
    ushortT* y2bf = (ushortT*)(ws + 16777216);     //  8 MiB
    ushortT* wb1  = (ushortT*)(ws + 25165824);     //  32 KiB
    ushortT* wb2  = (ushortT*)(ws + 25198592);     // 648 KiB
    ushortT* wb3  = (ushortT*)(ws + 25862144);     //  32 KiB
    float*   stats = (float*)(ws + 25894912);      // 8*768 floats = 24 KiB
    float*   coef1 = (float*)(ws + 25919488);      // 128 floats
    float*   coef2 = (float*)(ws + 25920000);      // 128 floats
    float* y3 = (float*)d_out;

    // grid covers 364544 weight elems + 6144 stats zeroing = 370688 = 1448*256
    k_prep_w     <<<1448,  256, 0, stream>>>(w1, w2, w3, wb1, wb2, wb3, stats);
    k_conv1_mfma <<<1024,  256, 0, stream>>>(x, wb1, y1bf, stats);
    k_coef       <<<1,     256, 0, stream>>>(stats, 0, 64, g1, b1, coef1);
    k_prep       <<<2048,  256, 0, stream>>>(y1bf, coef1, y1n);
    k_conv2_mfma <<<1024,  256, 0, stream>>>(y1n, wb2, stats, y2bf);
    k_coef       <<<1,     256, 0, stream>>>(stats, 128, 64, g2, b2, coef2);
    k_conv3_mfma <<<1024,  256, 0, stream>>>(y2bf, wb3, coef2, stats, y3);
    k_final      <<<16384, 256, 0, stream>>>(x, stats, g3, b3, y3);
}